// Round 9
// baseline (2312.691 us; speedup 1.0000x reference)
//
#include <hip/hip_runtime.h>
#include <math.h>

namespace {

constexpr int T_STEPS = 512;

typedef _Float16 h8v __attribute__((ext_vector_type(8)));
typedef _Float16 h4v __attribute__((ext_vector_type(4)));
typedef float    f4v __attribute__((ext_vector_type(4)));
typedef int      i4v __attribute__((ext_vector_type(4)));

__device__ __forceinline__ float sigf(float v) { return 1.0f / (1.0f + __expf(-v)); }
__device__ __forceinline__ float tanh_(float v) { return 2.0f / (1.0f + __expf(-2.0f * v)) - 1.0f; }

// Pack weights into MFMA B-fragment load order, fp16 (layout HW-verified R3+).
// Tile n (0..31) covers gates [16n,16n+16). Frag elem [l][j]: gate = 16n+(l&15),
// k = 32*ks + 8*(l>>4) + j.
// PA frag (n*6+ks): ks 0-1 = Wih0 (K=64), ks 2-5 = Whh0 (hh-ks 0..3).
// PB frag (n*8+ks): ks 0-3 = Wih1, ks 4-7 = Whh1.
__global__ void pack_w(const float* __restrict__ Wih0, const float* __restrict__ Whh0,
                       const float* __restrict__ Wih1, const float* __restrict__ Whh1,
                       _Float16* __restrict__ PA, _Float16* __restrict__ PB) {
  int idx = blockIdx.x * 256 + threadIdx.x;
  if (idx < 98304) {
    int j = idx & 7, l = (idx >> 3) & 63;
    int f = idx >> 9;
    int ks = f % 6, n = f / 6;
    int gate = 16 * n + (l & 15);
    int k = 32 * ks + ((l >> 4) << 3) + j;
    float v = (k < 64) ? Wih0[gate * 64 + k] : Whh0[gate * 128 + (k - 64)];
    PA[idx] = (_Float16)v;
  } else if (idx < 229376) {
    int i = idx - 98304;
    int j = i & 7, l = (i >> 3) & 63;
    int f = i >> 9;
    int ks = f & 7, n = f >> 3;
    int gate = 16 * n + (l & 15);
    int k = 32 * ks + ((l >> 4) << 3) + j;
    float v = (k < 128) ? Wih1[gate * 128 + k] : Whh1[gate * 128 + (k - 128)];
    PB[i] = (_Float16)v;
  }
}

// 64 blocks x 256 threads (4 waves, 1 wave/SIMD). Wave w owns units
// [32w,32w+32) x 4 gate types (q = 2t+s, tile n = 8t+2w+s) for BOTH layers --
// R7's HW-verified mapping. ZERO per-step global weight traffic:
//   AGPR (256 regs, "+a" anchors): Wih1 + Whh1 (64 frags/wave)
//   VGPR ("+v" anchors, ~64 regs): Whh0 hh-ks{0,1} (16 frags/wave)
//   LDS (148 KB): Wih0 (64 KB) + Whh0 hh-ks{2,3} (64 KB) + h/x tiles (20 KB)
// Fused pipeline: iter j = layer0 step j + layer1 step j-1, one barrier/iter.
// c state fp32 in registers; cell update lane-local.
__global__ __attribute__((amdgpu_waves_per_eu(1, 1))) __launch_bounds__(256)
void lstm_block(
    const float* __restrict__ x,
    const _Float16* __restrict__ PA, const _Float16* __restrict__ PB,
    const float* __restrict__ b0, const float* __restrict__ b1,
    const float* __restrict__ Wout, const float* __restrict__ bout,
    float* __restrict__ out) {
  extern __shared__ char smem[];
  h8v* wx     = (h8v*)smem;             // Wih0:  [32 n][2 ks][64 l] = 64 KB
  h8v* whh0l  = (h8v*)(smem + 65536);   // Whh0 hh-ks{2,3}: [32 n][2][64 l] = 64 KB
  _Float16(*h0t)[4][64][8] = (_Float16(*)[4][64][8])(smem + 131072);  // [2][4][64][8] 8 KB
  _Float16(*h1t)[4][64][8] = (_Float16(*)[4][64][8])(smem + 139264);  // 8 KB
  _Float16(*xt)[2][64][8]  = (_Float16(*)[2][64][8])(smem + 147456);  // [2][2][64][8] 4 KB

  const int tid = threadIdx.x;
  const int g = blockIdx.x;
  const int w = tid >> 6, l = tid & 63;
  const int lo = l & 15, hi = l >> 4;

  const h8v* PAv = (const h8v*)PA;
  const i4v* PBi = (const i4v*)PB;

  // ---- register-resident weights ----
  // Whh0 hh-ks 0,1 in VGPRs:
  h8v W0h[8][2];
  // Wih1 (W1A) + Whh1 (W1B) in AGPRs (int4 storage, bit-cast at use):
  i4v W1A[8][4], W1B[8][4];
#pragma unroll
  for (int t = 0; t < 4; ++t)
#pragma unroll
    for (int s = 0; s < 2; ++s) {
      int q = 2 * t + s, n = 8 * t + 2 * w + s;
#pragma unroll
      for (int ks = 0; ks < 2; ++ks) W0h[q][ks] = PAv[(n * 6 + 2 + ks) * 64 + l];
#pragma unroll
      for (int ks = 0; ks < 4; ++ks) {
        W1A[q][ks] = PBi[(n * 8 + ks) * 64 + l];
        W1B[q][ks] = PBi[(n * 8 + 4 + ks) * 64 + l];
      }
    }
#pragma unroll
  for (int q = 0; q < 8; ++q) {
#pragma unroll
    for (int ks = 0; ks < 2; ++ks) asm volatile("" : "+v"(W0h[q][ks]));
#pragma unroll
    for (int ks = 0; ks < 4; ++ks) {
      asm volatile("" : "+a"(W1A[q][ks]));
      asm volatile("" : "+a"(W1B[q][ks]));
    }
  }

  float bA[8], bB[8];
#pragma unroll
  for (int t = 0; t < 4; ++t)
#pragma unroll
    for (int s = 0; s < 2; ++s) {
      int q = 2 * t + s, gidx = 128 * t + 32 * w + 16 * s + lo;
      bA[q] = b0[gidx];
      bB[q] = b1[gidx];
    }
  float c0[2][4] = {{0.f, 0.f, 0.f, 0.f}, {0.f, 0.f, 0.f, 0.f}};
  float c1[2][4] = {{0.f, 0.f, 0.f, 0.f}, {0.f, 0.f, 0.f, 0.f}};

  // ---- stage LDS weights: Wih0 (ks 0,1) and Whh0 hh-ks 2,3 ----
  for (int i = tid; i < 4096; i += 256) {
    int n = i >> 7, kk = (i >> 6) & 1, ll = i & 63;
    wx[i]    = PAv[(n * 6 + kk) * 64 + ll];
    whh0l[i] = PAv[(n * 6 + 4 + kk) * 64 + ll];
  }
  // ---- zero h tiles, stage x(0) ----
  {
    unsigned int* z0 = (unsigned int*)h0t;
    unsigned int* z1 = (unsigned int*)h1t;
    for (int i = tid; i < 2048; i += 256) { z0[i] = 0u; z1[i] = 0u; }
    int row = tid >> 4, kk = (tid & 15) << 2;
    float4 v = *(const float4*)(x + (((long)(g * 16 + row)) * T_STEPS) * 64 + kk);
    h4v pv;
    pv.x = (_Float16)v.x; pv.y = (_Float16)v.y;
    pv.z = (_Float16)v.z; pv.w = (_Float16)v.w;
    *(h4v*)&xt[0][kk >> 5][(((kk >> 3) & 3) * 16) + row][kk & 7] = pv;
  }
  __syncthreads();

  // Fused: iter j = A(j) [layer0 step j] + B(j-1) [layer1 step j-1].
  for (int j = 0; j <= T_STEPS; ++j) {
    const int p = j & 1;
    h8v h00 = *(const h8v*)&h0t[p][0][l][0];
    h8v h01 = *(const h8v*)&h0t[p][1][l][0];
    h8v h02 = *(const h8v*)&h0t[p][2][l][0];
    h8v h03 = *(const h8v*)&h0t[p][3][l][0];

    if (j < T_STEPS) {
      h8v ax0 = *(const h8v*)&xt[p][0][l][0];
      h8v ax1 = *(const h8v*)&xt[p][1][l][0];
#pragma unroll
      for (int s = 0; s < 2; ++s) {
        f4v acc[4];
#pragma unroll
        for (int t = 0; t < 4; ++t) {
          int q = 2 * t + s, n = 8 * t + 2 * w + s;
          const h8v* wxp = wx + n * 128 + l;
          const h8v* w0p = whh0l + n * 128 + l;
          f4v z = {bA[q], bA[q], bA[q], bA[q]};
          z = __builtin_amdgcn_mfma_f32_16x16x32_f16(ax0, wxp[0], z, 0, 0, 0);
          z = __builtin_amdgcn_mfma_f32_16x16x32_f16(ax1, wxp[64], z, 0, 0, 0);
          z = __builtin_amdgcn_mfma_f32_16x16x32_f16(h00, W0h[q][0], z, 0, 0, 0);
          z = __builtin_amdgcn_mfma_f32_16x16x32_f16(h01, W0h[q][1], z, 0, 0, 0);
          z = __builtin_amdgcn_mfma_f32_16x16x32_f16(h02, w0p[0], z, 0, 0, 0);
          z = __builtin_amdgcn_mfma_f32_16x16x32_f16(h03, w0p[64], z, 0, 0, 0);
          acc[t] = z;
        }
#pragma unroll
        for (int r = 0; r < 4; ++r) {
          float cn = sigf(acc[1][r]) * c0[s][r] + sigf(acc[0][r]) * tanh_(acc[2][r]);
          c0[s][r] = cn;
          float hv = sigf(acc[3][r]) * tanh_(cn);
          h0t[p ^ 1][w][(2 * s + (lo >> 3)) * 16 + hi * 4 + r][lo & 7] = (_Float16)hv;
        }
      }
      if (j + 1 < T_STEPS) {  // stage x(j+1) -> xt[p^1]
        int row = tid >> 4, kk = (tid & 15) << 2;
        float4 v = *(const float4*)(x + (((long)(g * 16 + row)) * T_STEPS + (j + 1)) * 64 + kk);
        h4v pv;
        pv.x = (_Float16)v.x; pv.y = (_Float16)v.y;
        pv.z = (_Float16)v.z; pv.w = (_Float16)v.w;
        *(h4v*)&xt[p ^ 1][kk >> 5][(((kk >> 3) & 3) * 16) + row][kk & 7] = pv;
      }
    }

    if (j >= 1) {
      h8v f10 = *(const h8v*)&h1t[p][0][l][0];
      h8v f11 = *(const h8v*)&h1t[p][1][l][0];
      h8v f12 = *(const h8v*)&h1t[p][2][l][0];
      h8v f13 = *(const h8v*)&h1t[p][3][l][0];
#pragma unroll
      for (int s = 0; s < 2; ++s) {
        f4v acc[4];
#pragma unroll
        for (int t = 0; t < 4; ++t) {
          int q = 2 * t + s;
          f4v z = {bB[q], bB[q], bB[q], bB[q]};
          z = __builtin_amdgcn_mfma_f32_16x16x32_f16(h00, __builtin_bit_cast(h8v, W1A[q][0]), z, 0, 0, 0);
          z = __builtin_amdgcn_mfma_f32_16x16x32_f16(h01, __builtin_bit_cast(h8v, W1A[q][1]), z, 0, 0, 0);
          z = __builtin_amdgcn_mfma_f32_16x16x32_f16(h02, __builtin_bit_cast(h8v, W1A[q][2]), z, 0, 0, 0);
          z = __builtin_amdgcn_mfma_f32_16x16x32_f16(h03, __builtin_bit_cast(h8v, W1A[q][3]), z, 0, 0, 0);
          z = __builtin_amdgcn_mfma_f32_16x16x32_f16(f10, __builtin_bit_cast(h8v, W1B[q][0]), z, 0, 0, 0);
          z = __builtin_amdgcn_mfma_f32_16x16x32_f16(f11, __builtin_bit_cast(h8v, W1B[q][1]), z, 0, 0, 0);
          z = __builtin_amdgcn_mfma_f32_16x16x32_f16(f12, __builtin_bit_cast(h8v, W1B[q][2]), z, 0, 0, 0);
          z = __builtin_amdgcn_mfma_f32_16x16x32_f16(f13, __builtin_bit_cast(h8v, W1B[q][3]), z, 0, 0, 0);
          acc[t] = z;
        }
#pragma unroll
        for (int r = 0; r < 4; ++r) {
          float cn = sigf(acc[1][r]) * c1[s][r] + sigf(acc[0][r]) * tanh_(acc[2][r]);
          c1[s][r] = cn;
          float hv = sigf(acc[3][r]) * tanh_(cn);
          h1t[p ^ 1][w][(2 * s + (lo >> 3)) * 16 + hi * 4 + r][lo & 7] = (_Float16)hv;
        }
      }
    }
    __syncthreads();
  }

  // ---- output projection: y = h1(T-1) . Wout^T + bout ; h1(T-1) in h1t[1] ----
  if (tid < 16) {
    float acc = bout[0];
#pragma unroll 4
    for (int u = 0; u < 128; ++u) {
      float hval = (float)h1t[1][u >> 5][(((u >> 3) & 3) * 16) + tid][u & 7];
      acc = fmaf(hval, Wout[u], acc);
    }
    out[g * 16 + tid] = acc;
  }
}

}  // namespace

extern "C" void kernel_launch(void* const* d_in, const int* in_sizes, int n_in,
                              void* d_out, int out_size, void* d_ws, size_t ws_size,
                              hipStream_t stream) {
  const float* x    = (const float*)d_in[0];
  const float* Wih0 = (const float*)d_in[1];
  const float* Whh0 = (const float*)d_in[2];
  const float* b0   = (const float*)d_in[3];
  const float* Wih1 = (const float*)d_in[4];
  const float* Whh1 = (const float*)d_in[5];
  const float* b1   = (const float*)d_in[6];
  const float* Wout = (const float*)d_in[7];
  const float* bout = (const float*)d_in[8];
  float* out = (float*)d_out;

  char* ws = (char*)d_ws;
  _Float16* PA = (_Float16*)ws;             // 196608 B
  _Float16* PB = (_Float16*)(ws + 196608);  // 262144 B

  const int lds_bytes = 65536 + 65536 + 8192 + 8192 + 4096;  // 151552
  hipFuncSetAttribute((const void*)lstm_block,
                      hipFuncAttributeMaxDynamicSharedMemorySize, lds_bytes);

  pack_w<<<dim3(896), dim3(256), 0, stream>>>(Wih0, Whh0, Wih1, Whh1, PA, PB);
  lstm_block<<<dim3(64), dim3(256), lds_bytes, stream>>>(
      x, PA, PB, b0, b1, Wout, bout, out);
}

// Round 10
// 1879.926 us; speedup vs baseline: 1.2302x; 1.2302x over previous
//
#include <hip/hip_runtime.h>
#include <math.h>

namespace {

constexpr int T_STEPS = 512;

typedef _Float16 h8v __attribute__((ext_vector_type(8)));
typedef _Float16 h4v __attribute__((ext_vector_type(4)));
typedef float    f4v __attribute__((ext_vector_type(4)));
typedef int      i4v __attribute__((ext_vector_type(4)));

__device__ __forceinline__ float sigf(float v) { return 1.0f / (1.0f + __expf(-v)); }
__device__ __forceinline__ float tanh_(float v) { return 2.0f / (1.0f + __expf(-2.0f * v)) - 1.0f; }

// Pack weights into MFMA B-fragment load order, fp16 (layout HW-verified R3+).
// Tile n (0..31) covers gates [16n,16n+16). Frag elem [l][j]: gate = 16n+(l&15),
// k = 32*ks + 8*(l>>4) + j.
// PA frag (n*6+ks): ks 0-1 = Wih0 (K=64), ks 2-5 = Whh0 (hh k-slices 0..3).
// PB frag (n*8+ks): ks 0-3 = Wih1, ks 4-7 = Whh1.
__global__ void pack_w(const float* __restrict__ Wih0, const float* __restrict__ Whh0,
                       const float* __restrict__ Wih1, const float* __restrict__ Whh1,
                       _Float16* __restrict__ PA, _Float16* __restrict__ PB) {
  int idx = blockIdx.x * 256 + threadIdx.x;
  if (idx < 98304) {
    int j = idx & 7, l = (idx >> 3) & 63;
    int f = idx >> 9;
    int ks = f % 6, n = f / 6;
    int gate = 16 * n + (l & 15);
    int k = 32 * ks + ((l >> 4) << 3) + j;
    float v = (k < 64) ? Wih0[gate * 64 + k] : Whh0[gate * 128 + (k - 64)];
    PA[idx] = (_Float16)v;
  } else if (idx < 229376) {
    int i = idx - 98304;
    int j = i & 7, l = (i >> 3) & 63;
    int f = i >> 9;
    int ks = f & 7, n = f >> 3;
    int gate = 16 * n + (l & 15);
    int k = 32 * ks + ((l >> 4) << 3) + j;
    float v = (k < 128) ? Wih1[gate * 128 + k] : Whh1[gate * 128 + (k - 128)];
    PB[i] = (_Float16)v;
  }
}

// 64 blocks x 512 threads (8 waves, 2/SIMD). LAYER-SPLIT: waves 0-3 = layer0,
// waves 4-7 = layer1 (fused pipeline: iter j = L0 step j || L1 step j-1,
// independent, one barrier/iter). Wave w of its group owns units [32w,32w+32)
// x 4 gate types (q = 2t+s, tile n = 8t+2w+s) -- R7/R9 HW-verified mapping.
// Per-wave 256 unified regs = 128 AGPR weights ("+a", R9-proven no-spill) +
// 128 VGPR working set:
//   AGPR: L0 wave -> PA ks0-3 (Wih0 + Whh0 hh-ks0,1); L1 wave -> Wih1 ks0-3
//   LDS (148.5 KB): L0 hh-ks2,3 (64 KB) + L1 Whh1 ks4,5 (64 KB) + h/x tiles
//   L2 stream (64 KB/step, L2-hot, LICM-defeated): L1 Whh1 ks6,7
// c state fp32 in registers; cell update lane-local.
__global__ __attribute__((amdgpu_waves_per_eu(2, 2))) __launch_bounds__(512)
void lstm_block(
    const float* __restrict__ x,
    const _Float16* __restrict__ PA, const _Float16* __restrict__ PB,
    const float* __restrict__ b0, const float* __restrict__ b1,
    const float* __restrict__ Wout, const float* __restrict__ bout,
    float* __restrict__ out) {
  extern __shared__ char smem[];
  h8v* l0w = (h8v*)smem;            // L0 hh-ks{2,3}: [4 w][8 q][2 ks][64 l] = 64 KB
  h8v* l1w = (h8v*)(smem + 65536);  // L1 Whh1 ks4,5: [4 w][8 q][2 ks][64 l] = 64 KB
  _Float16(*h0t)[4][64][8] = (_Float16(*)[4][64][8])(smem + 131072);  // [2][4][64][8] 8 KB
  _Float16(*h1t)[4][64][8] = (_Float16(*)[4][64][8])(smem + 139264);  // 8 KB
  _Float16(*xt)[2][64][8]  = (_Float16(*)[2][64][8])(smem + 147456);  // [2][2][64][8] 4 KB

  const int tid = threadIdx.x;
  const int g = blockIdx.x;
  const int wv = tid >> 6, l = tid & 63;
  const int lo = l & 15, hi = l >> 4;
  const bool isL0 = (wv < 4);
  const int w = isL0 ? wv : (wv - 4);

  const i4v* PAi = (const i4v*)PA;
  const i4v* PBi = (const i4v*)PB;

  // ---- AGPR-resident weights: 32 frags/wave, content layer-dependent ----
  i4v WR[8][4];
#pragma unroll
  for (int t = 0; t < 4; ++t)
#pragma unroll
    for (int s = 0; s < 2; ++s) {
      int q = 2 * t + s, n = 8 * t + 2 * w + s;
#pragma unroll
      for (int ks = 0; ks < 4; ++ks)
        WR[q][ks] = isL0 ? PAi[(n * 6 + ks) * 64 + l]
                         : PBi[(n * 8 + ks) * 64 + l];
    }
#pragma unroll
  for (int q = 0; q < 8; ++q)
#pragma unroll
    for (int ks = 0; ks < 4; ++ks) asm volatile("" : "+a"(WR[q][ks]));

  float br[8];
#pragma unroll
  for (int t = 0; t < 4; ++t)
#pragma unroll
    for (int s = 0; s < 2; ++s) {
      int q = 2 * t + s, gidx = 128 * t + 32 * w + 16 * s + lo;
      br[q] = isL0 ? b0[gidx] : b1[gidx];
    }
  float cs[2][4] = {{0.f, 0.f, 0.f, 0.f}, {0.f, 0.f, 0.f, 0.f}};

  // ---- stage LDS weights (wave-private slices) ----
  for (int i = tid; i < 4096; i += 512) {
    int ll = i & 63, ks = (i >> 6) & 1, q = (i >> 7) & 7, ww = (i >> 10) & 3;
    int n = 8 * (q >> 1) + 2 * ww + (q & 1);
    ((i4v*)l0w)[i] = PAi[(n * 6 + 4 + ks) * 64 + ll];
    ((i4v*)l1w)[i] = PBi[(n * 8 + 4 + ks) * 64 + ll];
  }
  // ---- zero h tiles, stage x(0) ----
  {
    unsigned int* z0 = (unsigned int*)h0t;
    unsigned int* z1 = (unsigned int*)h1t;
    for (int i = tid; i < 2048; i += 512) { z0[i] = 0u; z1[i] = 0u; }
    if (tid < 256) {
      int row = tid >> 4, kk = (tid & 15) << 2;
      float4 v = *(const float4*)(x + (((long)(g * 16 + row)) * T_STEPS) * 64 + kk);
      h4v pv;
      pv.x = (_Float16)v.x; pv.y = (_Float16)v.y;
      pv.z = (_Float16)v.z; pv.w = (_Float16)v.w;
      *(h4v*)&xt[0][kk >> 5][(((kk >> 3) & 3) * 16) + row][kk & 7] = pv;
    }
  }
  __syncthreads();

  // Fused: iter j = L0 step j (waves 0-3) || L1 step j-1 (waves 4-7).
  for (int j = 0; j <= T_STEPS; ++j) {
    const int p = j & 1;

    if (isL0) {
      if (j < T_STEPS) {
        h8v h00 = *(const h8v*)&h0t[p][0][l][0];
        h8v h01 = *(const h8v*)&h0t[p][1][l][0];
        h8v h02 = *(const h8v*)&h0t[p][2][l][0];
        h8v h03 = *(const h8v*)&h0t[p][3][l][0];
        h8v ax0 = *(const h8v*)&xt[p][0][l][0];
        h8v ax1 = *(const h8v*)&xt[p][1][l][0];
#pragma unroll
        for (int s = 0; s < 2; ++s) {
          f4v acc[4];
#pragma unroll
          for (int t = 0; t < 4; ++t) {
            int q = 2 * t + s;
            const h8v* lw = l0w + ((w * 8 + q) * 2) * 64 + l;
            f4v z = {br[q], br[q], br[q], br[q]};
            z = __builtin_amdgcn_mfma_f32_16x16x32_f16(ax0, __builtin_bit_cast(h8v, WR[q][0]), z, 0, 0, 0);
            z = __builtin_amdgcn_mfma_f32_16x16x32_f16(ax1, __builtin_bit_cast(h8v, WR[q][1]), z, 0, 0, 0);
            z = __builtin_amdgcn_mfma_f32_16x16x32_f16(h00, __builtin_bit_cast(h8v, WR[q][2]), z, 0, 0, 0);
            z = __builtin_amdgcn_mfma_f32_16x16x32_f16(h01, __builtin_bit_cast(h8v, WR[q][3]), z, 0, 0, 0);
            z = __builtin_amdgcn_mfma_f32_16x16x32_f16(h02, lw[0], z, 0, 0, 0);
            z = __builtin_amdgcn_mfma_f32_16x16x32_f16(h03, lw[64], z, 0, 0, 0);
            acc[t] = z;
          }
#pragma unroll
          for (int r = 0; r < 4; ++r) {
            float cn = sigf(acc[1][r]) * cs[s][r] + sigf(acc[0][r]) * tanh_(acc[2][r]);
            cs[s][r] = cn;
            float hv = sigf(acc[3][r]) * tanh_(cn);
            h0t[p ^ 1][w][(2 * s + (lo >> 3)) * 16 + hi * 4 + r][lo & 7] = (_Float16)hv;
          }
        }
        if (j + 1 < T_STEPS) {  // stage x(j+1) -> xt[p^1] (L0 threads = tid<256)
          int row = tid >> 4, kk = (tid & 15) << 2;
          float4 v = *(const float4*)(x + (((long)(g * 16 + row)) * T_STEPS + (j + 1)) * 64 + kk);
          h4v pv;
          pv.x = (_Float16)v.x; pv.y = (_Float16)v.y;
          pv.z = (_Float16)v.z; pv.w = (_Float16)v.w;
          *(h4v*)&xt[p ^ 1][kk >> 5][(((kk >> 3) & 3) * 16) + row][kk & 7] = pv;
        }
      }
    } else {
      if (j >= 1) {
        int zero = 0;
        asm volatile("" : "+v"(zero));  // defeat LICM on the L2-streamed frags
        h8v h00 = *(const h8v*)&h0t[p][0][l][0];
        h8v h01 = *(const h8v*)&h0t[p][1][l][0];
        h8v h02 = *(const h8v*)&h0t[p][2][l][0];
        h8v h03 = *(const h8v*)&h0t[p][3][l][0];
        h8v f10 = *(const h8v*)&h1t[p][0][l][0];
        h8v f11 = *(const h8v*)&h1t[p][1][l][0];
        h8v f12 = *(const h8v*)&h1t[p][2][l][0];
        h8v f13 = *(const h8v*)&h1t[p][3][l][0];
#pragma unroll
        for (int s = 0; s < 2; ++s) {
          f4v acc[4];
#pragma unroll
          for (int t = 0; t < 4; ++t) {
            int q = 2 * t + s, n = 8 * t + 2 * w + s;
            h8v gw0 = __builtin_bit_cast(h8v, PBi[(n * 8 + 6) * 64 + l + zero]);
            h8v gw1 = __builtin_bit_cast(h8v, PBi[(n * 8 + 7) * 64 + l + zero]);
            const h8v* lw = l1w + ((w * 8 + q) * 2) * 64 + l;
            f4v z = {br[q], br[q], br[q], br[q]};
            z = __builtin_amdgcn_mfma_f32_16x16x32_f16(h00, __builtin_bit_cast(h8v, WR[q][0]), z, 0, 0, 0);
            z = __builtin_amdgcn_mfma_f32_16x16x32_f16(h01, __builtin_bit_cast(h8v, WR[q][1]), z, 0, 0, 0);
            z = __builtin_amdgcn_mfma_f32_16x16x32_f16(h02, __builtin_bit_cast(h8v, WR[q][2]), z, 0, 0, 0);
            z = __builtin_amdgcn_mfma_f32_16x16x32_f16(h03, __builtin_bit_cast(h8v, WR[q][3]), z, 0, 0, 0);
            z = __builtin_amdgcn_mfma_f32_16x16x32_f16(f10, lw[0], z, 0, 0, 0);
            z = __builtin_amdgcn_mfma_f32_16x16x32_f16(f11, lw[64], z, 0, 0, 0);
            z = __builtin_amdgcn_mfma_f32_16x16x32_f16(f12, gw0, z, 0, 0, 0);
            z = __builtin_amdgcn_mfma_f32_16x16x32_f16(f13, gw1, z, 0, 0, 0);
            acc[t] = z;
          }
#pragma unroll
          for (int r = 0; r < 4; ++r) {
            float cn = sigf(acc[1][r]) * cs[s][r] + sigf(acc[0][r]) * tanh_(acc[2][r]);
            cs[s][r] = cn;
            float hv = sigf(acc[3][r]) * tanh_(cn);
            h1t[p ^ 1][w][(2 * s + (lo >> 3)) * 16 + hi * 4 + r][lo & 7] = (_Float16)hv;
          }
        }
      }
    }
    __syncthreads();
  }

  // ---- output projection: y = h1(T-1) . Wout^T + bout ; h1(T-1) in h1t[1] ----
  if (tid < 16) {
    float acc = bout[0];
#pragma unroll 4
    for (int u = 0; u < 128; ++u) {
      float hval = (float)h1t[1][u >> 5][(((u >> 3) & 3) * 16) + tid][u & 7];
      acc = fmaf(hval, Wout[u], acc);
    }
    out[g * 16 + tid] = acc;
  }
}

}  // namespace

extern "C" void kernel_launch(void* const* d_in, const int* in_sizes, int n_in,
                              void* d_out, int out_size, void* d_ws, size_t ws_size,
                              hipStream_t stream) {
  const float* x    = (const float*)d_in[0];
  const float* Wih0 = (const float*)d_in[1];
  const float* Whh0 = (const float*)d_in[2];
  const float* b0   = (const float*)d_in[3];
  const float* Wih1 = (const float*)d_in[4];
  const float* Whh1 = (const float*)d_in[5];
  const float* b1   = (const float*)d_in[6];
  const float* Wout = (const float*)d_in[7];
  const float* bout = (const float*)d_in[8];
  float* out = (float*)d_out;

  char* ws = (char*)d_ws;
  _Float16* PA = (_Float16*)ws;             // 196608 B
  _Float16* PB = (_Float16*)(ws + 196608);  // 262144 B

  const int lds_bytes = 65536 + 65536 + 8192 + 8192 + 4096;  // 151552
  hipFuncSetAttribute((const void*)lstm_block,
                      hipFuncAttributeMaxDynamicSharedMemorySize, lds_bytes);

  pack_w<<<dim3(896), dim3(256), 0, stream>>>(Wih0, Whh0, Wih1, Whh1, PA, PB);
  lstm_block<<<dim3(64), dim3(512), lds_bytes, stream>>>(
      x, PA, PB, b0, b1, Wout, bout, out);
}